// Round 1
// baseline (328.427 us; speedup 1.0000x reference)
//
#include <hip/hip_runtime.h>
#include <hip/hip_bf16.h>

// Problem constants
#define Bb 2
#define Nn 4096
#define Cc 1024
#define Hh 16
#define Dd 64
#define Mm (Bb*Nn)      // 8192
#define W2 10
#define WINSZ 21        // 2*W2+1

typedef __attribute__((ext_vector_type(8))) short  bf16x8s;
typedef __attribute__((ext_vector_type(4))) float  f32x4;
typedef __attribute__((ext_vector_type(4))) unsigned short us4;

#define AS1 __attribute__((address_space(1)))
#define AS3 __attribute__((address_space(3)))

__device__ __forceinline__ unsigned short f2bf(float f) {
  unsigned int u = __float_as_uint(f);
  u += 0x7FFFu + ((u >> 16) & 1u);
  return (unsigned short)(u >> 16);
}
__device__ __forceinline__ float bf2f(unsigned short h) {
  return __uint_as_float(((unsigned int)h) << 16);
}

// ---------------- fp32 -> bf16 convert (vectorized) ----------------
__global__ __launch_bounds__(256) void f2bf_kernel(const float4* __restrict__ src,
                                                   us4* __restrict__ dst, int n4) {
  int stride = gridDim.x * 256;
  for (int i = blockIdx.x * 256 + threadIdx.x; i < n4; i += stride) {
    float4 v = src[i];
    us4 o;
    o.x = f2bf(v.x); o.y = f2bf(v.y); o.z = f2bf(v.z); o.w = f2bf(v.w);
    dst[i] = o;
  }
}

// ---------------- bf16 NT GEMM: C[m,n] = sum_k A[m,k]*B[n,k] + bias[n] ----------------
// m97 structure: 128x128 tile, BK=64, 4 waves (2x2), 4x4 16x16x32 frags per wave.
template<bool OUT_BF16>
__global__ __launch_bounds__(256) void gemm_bt(const unsigned short* __restrict__ A,
                                               const unsigned short* __restrict__ Bm,
                                               const float* __restrict__ bias,
                                               void* __restrict__ Cout,
                                               int M, int N, int K) {
  constexpr int BM = 128, BN = 128, BK = 64;
  __shared__ unsigned short As[BM * BK];   // 16 KB, row-major [BM][BK]
  __shared__ unsigned short Bs[BN * BK];   // 16 KB

  const int tid  = threadIdx.x;
  const int wave = tid >> 6, lane = tid & 63;
  const int wr = wave >> 1, wc = wave & 1;
  const int m0 = blockIdx.y * BM, n0 = blockIdx.x * BN;

  f32x4 acc[4][4] = {};

  // staging source addresses: instruction i covers elements [i*512, i*512+512)
  // of the row-major [128][64] tile; lane l covers 8 contiguous bf16.
  const unsigned short* aSrc[4];
  const unsigned short* bSrc[4];
#pragma unroll
  for (int j = 0; j < 4; ++j) {
    int i = wave * 4 + j;
    int e = i * 512 + lane * 8;
    int row = e >> 6, col = e & 63;
    aSrc[j] = A  + (size_t)(m0 + row) * K + col;
    bSrc[j] = Bm + (size_t)(n0 + row) * K + col;
  }

  for (int k0 = 0; k0 < K; k0 += BK) {
    __syncthreads();  // previous-iter LDS reads done
#pragma unroll
    for (int j = 0; j < 4; ++j) {
      int i = wave * 4 + j;
      __builtin_amdgcn_global_load_lds((AS1 const void*)(aSrc[j] + k0),
                                       (AS3 void*)(&As[i * 512]), 16, 0, 0);
      __builtin_amdgcn_global_load_lds((AS1 const void*)(bSrc[j] + k0),
                                       (AS3 void*)(&Bs[i * 512]), 16, 0, 0);
    }
    __syncthreads();  // staging complete (compiler drains vmcnt before barrier)

#pragma unroll
    for (int kk = 0; kk < BK; kk += 32) {
      bf16x8s a[4], b[4];
#pragma unroll
      for (int m = 0; m < 4; ++m)
        a[m] = *(const bf16x8s*)&As[(wr * 64 + m * 16 + (lane & 15)) * BK + kk + (lane >> 4) * 8];
#pragma unroll
      for (int n = 0; n < 4; ++n)
        b[n] = *(const bf16x8s*)&Bs[(wc * 64 + n * 16 + (lane & 15)) * BK + kk + (lane >> 4) * 8];
#pragma unroll
      for (int m = 0; m < 4; ++m)
#pragma unroll
        for (int n = 0; n < 4; ++n)
          acc[m][n] = __builtin_amdgcn_mfma_f32_16x16x32_bf16(a[m], b[n], acc[m][n], 0, 0, 0);
    }
  }

  // epilogue: C/D layout col=lane&15, row=(lane>>4)*4+r  (guide §3, m89-verified)
#pragma unroll
  for (int m = 0; m < 4; ++m) {
#pragma unroll
    for (int n = 0; n < 4; ++n) {
#pragma unroll
      for (int r = 0; r < 4; ++r) {
        int row = m0 + wr * 64 + m * 16 + (lane >> 4) * 4 + r;
        int col = n0 + wc * 64 + n * 16 + (lane & 15);
        float v = acc[m][n][r] + bias[col];
        if (OUT_BF16)
          ((unsigned short*)Cout)[(size_t)row * N + col] = f2bf(v);
        else
          ((float*)Cout)[(size_t)row * N + col] = v;
      }
    }
  }
}

// ---------------- banded local attention ----------------
// grid: Bb*Hh*(Nn/64) blocks; block = 256 threads (4 waves); wave handles 16 n's.
#define TN 64
#define KVR (TN + 2 * W2)   // 84 rows staged

__global__ __launch_bounds__(256) void attn_kernel(const unsigned short* __restrict__ QKV, // [Mm][3072]
                                                   unsigned short* __restrict__ AO,        // [Mm][1024]
                                                   float* __restrict__ attn_last) {        // [Bb*Hh*11]
  __shared__ unsigned short Kl[KVR][Dd];
  __shared__ unsigned short Vl[KVR][Dd];

  const int nt = Nn / TN;                 // 64
  const int bid = blockIdx.x;
  const int tile = bid % nt;
  const int bh = bid / nt;
  const int h = bh % Hh, b = bh / Hh;
  const int n0 = tile * TN;
  const int tid = threadIdx.x;

  // stage K,V rows [n0-10, n0+73] (zero-fill out-of-range)
  for (int idx = tid; idx < KVR * 8; idx += 256) {
    int r = idx >> 3, sub = idx & 7;
    int pos = n0 - W2 + r;
    uint4 kv = make_uint4(0, 0, 0, 0), vv = kv;
    if (pos >= 0 && pos < Nn) {
      const unsigned short* base = QKV + (size_t)(b * Nn + pos) * 3072 + h * Dd + sub * 8;
      kv = *(const uint4*)(base + 1024);
      vv = *(const uint4*)(base + 2048);
    }
    *(uint4*)(&Kl[r][sub * 8]) = kv;
    *(uint4*)(&Vl[r][sub * 8]) = vv;
  }
  __syncthreads();

  const int wave = tid >> 6, lane = tid & 63;
#pragma unroll 1
  for (int i = 0; i < 16; ++i) {
    const int n = n0 + wave * 16 + i;
    const size_t m = (size_t)b * Nn + n;
    const float qf = bf2f(QKV[m * 3072 + h * Dd + lane]);

    float s[WINSZ];
#pragma unroll
    for (int w = 0; w < WINSZ; ++w) {
      int r = wave * 16 + i + w;
      float prod = qf * bf2f(Kl[r][lane]);
#pragma unroll
      for (int off = 32; off >= 1; off >>= 1) prod += __shfl_xor(prod, off, 64);
      s[w] = prod * 0.125f;  // 1/sqrt(64)
    }
#pragma unroll
    for (int w = 0; w < WINSZ; ++w) {
      int pos = n - W2 + w;
      if (pos < 0 || pos >= Nn) s[w] = -1e30f;
    }
    float mx = s[0];
#pragma unroll
    for (int w = 1; w < WINSZ; ++w) mx = fmaxf(mx, s[w]);
    float sum = 0.f;
#pragma unroll
    for (int w = 0; w < WINSZ; ++w) { s[w] = __expf(s[w] - mx); sum += s[w]; }
    const float inv = 1.0f / sum;

    float o = 0.f;
#pragma unroll
    for (int w = 0; w < WINSZ; ++w) o += s[w] * bf2f(Vl[wave * 16 + i + w][lane]);
    AO[m * Cc + h * Dd + lane] = f2bf(o * inv);

    if (n == Nn - 1) {
#pragma unroll
      for (int w = 0; w <= W2; ++w)
        if (lane == w) attn_last[(b * Hh + h) * (W2 + 1) + w] = s[w] * inv;
    }
  }
}

// ---------------- launch ----------------
extern "C" void kernel_launch(void* const* d_in, const int* in_sizes, int n_in,
                              void* d_out, int out_size, void* d_ws, size_t ws_size,
                              hipStream_t stream) {
  const float* q    = (const float*)d_in[0];
  const float* Wq_w = (const float*)d_in[1];
  const float* Wq_b = (const float*)d_in[2];
  const float* Wk_w = (const float*)d_in[3];
  const float* Wk_b = (const float*)d_in[4];
  const float* Wv_w = (const float*)d_in[5];
  const float* Wv_b = (const float*)d_in[6];
  const float* Wo_w = (const float*)d_in[7];
  const float* Wo_b = (const float*)d_in[8];
  float* out = (float*)d_out;                       // [Mm*Cc] + [Bb*Hh*11]
  float* attn_last = out + (size_t)Mm * Cc;

  // workspace carve (bytes)
  char* ws = (char*)d_ws;
  unsigned short* qb   = (unsigned short*)(ws);                       // Mm*Cc bf16   = 16 MB
  unsigned short* Wqkv = (unsigned short*)(ws + 16777216);            // 3072*1024    = 6 MB
  unsigned short* Wo16 = (unsigned short*)(ws + 16777216 + 6291456);  // 1024*1024    = 2 MB
  float*          bqkv = (float*)(ws + 25165824);                     // 3072 f32
  unsigned short* QKV  = (unsigned short*)(ws + 25182208);            // Mm*3072      = 48 MB
  unsigned short* AO   = (unsigned short*)(ws + 75513856);            // Mm*Cc        = 16 MB

  // 1) converts
  {
    int n4 = (Mm * Cc) / 4;
    f2bf_kernel<<<2048, 256, 0, stream>>>((const float4*)q, (us4*)qb, n4);
    int w4 = (Cc * Cc) / 4;
    f2bf_kernel<<<1024, 256, 0, stream>>>((const float4*)Wq_w, (us4*)(Wqkv), w4);
    f2bf_kernel<<<1024, 256, 0, stream>>>((const float4*)Wk_w, (us4*)(Wqkv + Cc * Cc), w4);
    f2bf_kernel<<<1024, 256, 0, stream>>>((const float4*)Wv_w, (us4*)(Wqkv + 2 * Cc * Cc), w4);
    f2bf_kernel<<<1024, 256, 0, stream>>>((const float4*)Wo_w, (us4*)Wo16, w4);
    hipMemcpyAsync(bqkv,          Wq_b, Cc * sizeof(float), hipMemcpyDeviceToDevice, stream);
    hipMemcpyAsync(bqkv + Cc,     Wk_b, Cc * sizeof(float), hipMemcpyDeviceToDevice, stream);
    hipMemcpyAsync(bqkv + 2 * Cc, Wv_b, Cc * sizeof(float), hipMemcpyDeviceToDevice, stream);
  }

  // 2) fused QKV projection: [8192,1024] x [3072,1024]^T -> bf16 [8192,3072]
  {
    dim3 grid(3072 / 128, Mm / 128);
    gemm_bt<true><<<grid, 256, 0, stream>>>(qb, Wqkv, bqkv, (void*)QKV, Mm, 3072, Cc);
  }

  // 3) windowed attention -> bf16 [8192,1024] + attn_last tail of d_out
  {
    dim3 grid(Bb * Hh * (Nn / TN));
    attn_kernel<<<grid, 256, 0, stream>>>(QKV, AO, attn_last);
  }

  // 4) output projection: [8192,1024] x [1024,1024]^T -> fp32 d_out
  {
    dim3 grid(Cc / 128, Mm / 128);
    gemm_bt<false><<<grid, 256, 0, stream>>>(AO, Wo16, Wo_b, (void*)out, Mm, Cc, Cc);
  }
}

// Round 2
// 184.590 us; speedup vs baseline: 1.7792x; 1.7792x over previous
//
#include <hip/hip_runtime.h>
#include <hip/hip_bf16.h>

// Problem constants
#define Bb 2
#define Nn 4096
#define Cc 1024
#define Hh 16
#define Dd 64
#define Mm (Bb*Nn)      // 8192
#define W2 10
#define WINSZ 21        // 2*W2+1

typedef __attribute__((ext_vector_type(8))) short  bf16x8s;
typedef __attribute__((ext_vector_type(4))) float  f32x4;
typedef __attribute__((ext_vector_type(4))) unsigned short us4;

#define AS1 __attribute__((address_space(1)))
#define AS3 __attribute__((address_space(3)))

__device__ __forceinline__ unsigned short f2bf(float f) {
  unsigned int u = __float_as_uint(f);
  u += 0x7FFFu + ((u >> 16) & 1u);
  return (unsigned short)(u >> 16);
}
__device__ __forceinline__ float bf2f(unsigned short h) {
  return __uint_as_float(((unsigned int)h) << 16);
}
// bf16 pair in a dword -> two floats (1 VALU op each)
__device__ __forceinline__ float bflo(unsigned int u) { return __uint_as_float(u << 16); }
__device__ __forceinline__ float bfhi(unsigned int u) { return __uint_as_float(u & 0xFFFF0000u); }

// ---------------- fp32 -> bf16 convert (vectorized) ----------------
__global__ __launch_bounds__(256) void f2bf_kernel(const float4* __restrict__ src,
                                                   us4* __restrict__ dst, int n4) {
  int stride = gridDim.x * 256;
  for (int i = blockIdx.x * 256 + threadIdx.x; i < n4; i += stride) {
    float4 v = src[i];
    us4 o;
    o.x = f2bf(v.x); o.y = f2bf(v.y); o.z = f2bf(v.z); o.w = f2bf(v.w);
    dst[i] = o;
  }
}

// ---------------- bf16 NT GEMM: C[m,n] = sum_k A[m,k]*B[n,k] + bias[n] ----------------
// m97 structure: 128x128 tile, BK=64, 4 waves (2x2), 4x4 16x16x32 frags per wave.
template<bool OUT_BF16>
__global__ __launch_bounds__(256) void gemm_bt(const unsigned short* __restrict__ A,
                                               const unsigned short* __restrict__ Bm,
                                               const float* __restrict__ bias,
                                               void* __restrict__ Cout,
                                               int M, int N, int K) {
  constexpr int BM = 128, BN = 128, BK = 64;
  __shared__ unsigned short As[BM * BK];   // 16 KB, row-major [BM][BK]
  __shared__ unsigned short Bs[BN * BK];   // 16 KB

  const int tid  = threadIdx.x;
  const int wave = tid >> 6, lane = tid & 63;
  const int wr = wave >> 1, wc = wave & 1;
  const int m0 = blockIdx.y * BM, n0 = blockIdx.x * BN;

  f32x4 acc[4][4] = {};

  const unsigned short* aSrc[4];
  const unsigned short* bSrc[4];
#pragma unroll
  for (int j = 0; j < 4; ++j) {
    int i = wave * 4 + j;
    int e = i * 512 + lane * 8;
    int row = e >> 6, col = e & 63;
    aSrc[j] = A  + (size_t)(m0 + row) * K + col;
    bSrc[j] = Bm + (size_t)(n0 + row) * K + col;
  }

  for (int k0 = 0; k0 < K; k0 += BK) {
    __syncthreads();
#pragma unroll
    for (int j = 0; j < 4; ++j) {
      int i = wave * 4 + j;
      __builtin_amdgcn_global_load_lds((AS1 const void*)(aSrc[j] + k0),
                                       (AS3 void*)(&As[i * 512]), 16, 0, 0);
      __builtin_amdgcn_global_load_lds((AS1 const void*)(bSrc[j] + k0),
                                       (AS3 void*)(&Bs[i * 512]), 16, 0, 0);
    }
    __syncthreads();

#pragma unroll
    for (int kk = 0; kk < BK; kk += 32) {
      bf16x8s a[4], b[4];
#pragma unroll
      for (int m = 0; m < 4; ++m)
        a[m] = *(const bf16x8s*)&As[(wr * 64 + m * 16 + (lane & 15)) * BK + kk + (lane >> 4) * 8];
#pragma unroll
      for (int n = 0; n < 4; ++n)
        b[n] = *(const bf16x8s*)&Bs[(wc * 64 + n * 16 + (lane & 15)) * BK + kk + (lane >> 4) * 8];
#pragma unroll
      for (int m = 0; m < 4; ++m)
#pragma unroll
        for (int n = 0; n < 4; ++n)
          acc[m][n] = __builtin_amdgcn_mfma_f32_16x16x32_bf16(a[m], b[n], acc[m][n], 0, 0, 0);
    }
  }

#pragma unroll
  for (int m = 0; m < 4; ++m) {
#pragma unroll
    for (int n = 0; n < 4; ++n) {
#pragma unroll
      for (int r = 0; r < 4; ++r) {
        int row = m0 + wr * 64 + m * 16 + (lane >> 4) * 4 + r;
        int col = n0 + wc * 64 + n * 16 + (lane & 15);
        float v = acc[m][n][r] + bias[col];
        if (OUT_BF16)
          ((unsigned short*)Cout)[(size_t)row * N + col] = f2bf(v);
        else
          ((float*)Cout)[(size_t)row * N + col] = v;
      }
    }
  }
}

// ---------------- banded local attention: one thread per (b,h,n) row ----------------
#define TN 128
#define KVROWS (TN + 2 * W2)   // 148 staged rows

__global__ __launch_bounds__(128) void attn_kernel(const unsigned short* __restrict__ QKV, // [Mm][3072]
                                                   unsigned short* __restrict__ AO,        // [Mm][1024]
                                                   float* __restrict__ attn_last) {        // [Bb*Hh*11]
  // K/V window in LDS, 16B chunks, XOR-swizzled: slot = c ^ (r&7)
  __shared__ uint4 Kl[KVROWS * 8];   // 18944 B
  __shared__ uint4 Vl[KVROWS * 8];   // 18944 B

  const int nt = Nn / TN;            // 32
  const int bid = blockIdx.x;
  const int tile = bid & (nt - 1);
  const int bh = bid / nt;
  const int h = bh & (Hh - 1), b = bh / Hh;
  const int n0 = tile * TN;
  const int tid = threadIdx.x;

  // stage K,V rows [n0-10, n0+137], zero-fill OOB, swizzled chunk placement
  for (int idx = tid; idx < KVROWS * 8; idx += 128) {
    const int r = idx >> 3, c = idx & 7;
    const int pos = n0 - W2 + r;
    uint4 kv = make_uint4(0, 0, 0, 0), vv = make_uint4(0, 0, 0, 0);
    if (pos >= 0 && pos < Nn) {
      const uint4* row = (const uint4*)(QKV + (size_t)(b * Nn + pos) * 3072);
      kv = row[128 + h * 8 + c];   // K block at elem 1024
      vv = row[256 + h * 8 + c];   // V block at elem 2048
    }
    const int slot = c ^ (r & 7);
    Kl[r * 8 + slot] = kv;
    Vl[r * 8 + slot] = vv;
  }
  __syncthreads();

  const int n = n0 + tid;
  const size_t m = (size_t)b * Nn + n;

  // q row -> 64 f32 regs
  const uint4* qrow = (const uint4*)(QKV + m * 3072) + h * 8;
  float qf[64];
#pragma unroll
  for (int c = 0; c < 8; ++c) {
    uint4 v = qrow[c];
    const unsigned int dw[4] = {v.x, v.y, v.z, v.w};
#pragma unroll
    for (int j = 0; j < 4; ++j) {
      qf[c * 8 + j * 2 + 0] = bflo(dw[j]);
      qf[c * 8 + j * 2 + 1] = bfhi(dw[j]);
    }
  }

  // scores: 21 lane-local dots of length 64 against swizzled LDS K
  float p[WINSZ];
#pragma unroll
  for (int w = 0; w < WINSZ; ++w) {
    const int r = tid + w;
    float acc = 0.f;
#pragma unroll
    for (int c = 0; c < 8; ++c) {
      uint4 v = Kl[r * 8 + (c ^ (r & 7))];
      const unsigned int dw[4] = {v.x, v.y, v.z, v.w};
#pragma unroll
      for (int j = 0; j < 4; ++j) {
        acc += qf[c * 8 + j * 2 + 0] * bflo(dw[j]);
        acc += qf[c * 8 + j * 2 + 1] * bfhi(dw[j]);
      }
    }
    p[w] = acc * 0.125f;   // 1/sqrt(64)
  }

  // mask + softmax (f32)
#pragma unroll
  for (int w = 0; w < WINSZ; ++w) {
    const int pos = n - W2 + w;
    if (pos < 0 || pos >= Nn) p[w] = -1e30f;
  }
  float mx = p[0];
#pragma unroll
  for (int w = 1; w < WINSZ; ++w) mx = fmaxf(mx, p[w]);
  float sum = 0.f;
#pragma unroll
  for (int w = 0; w < WINSZ; ++w) { p[w] = __expf(p[w] - mx); sum += p[w]; }
  const float inv = 1.0f / sum;

  // P·V
  float o[64] = {};
#pragma unroll
  for (int w = 0; w < WINSZ; ++w) {
    const int r = tid + w;
    const float pw = p[w];
#pragma unroll
    for (int c = 0; c < 8; ++c) {
      uint4 v = Vl[r * 8 + (c ^ (r & 7))];
      const unsigned int dw[4] = {v.x, v.y, v.z, v.w};
#pragma unroll
      for (int j = 0; j < 4; ++j) {
        o[c * 8 + j * 2 + 0] += pw * bflo(dw[j]);
        o[c * 8 + j * 2 + 1] += pw * bfhi(dw[j]);
      }
    }
  }

  // packed bf16 writeout
  uint4* orow = (uint4*)(AO + m * Cc + h * Dd);
#pragma unroll
  for (int c = 0; c < 8; ++c) {
    unsigned int dw[4];
#pragma unroll
    for (int j = 0; j < 4; ++j) {
      float e0 = o[c * 8 + j * 2 + 0] * inv;
      float e1 = o[c * 8 + j * 2 + 1] * inv;
      dw[j] = (unsigned int)f2bf(e0) | ((unsigned int)f2bf(e1) << 16);
    }
    orow[c] = make_uint4(dw[0], dw[1], dw[2], dw[3]);
  }

  if (n == Nn - 1) {
#pragma unroll
    for (int w = 0; w <= W2; ++w)
      attn_last[(b * Hh + h) * (W2 + 1) + w] = p[w] * inv;
  }
}

// ---------------- launch ----------------
extern "C" void kernel_launch(void* const* d_in, const int* in_sizes, int n_in,
                              void* d_out, int out_size, void* d_ws, size_t ws_size,
                              hipStream_t stream) {
  const float* q    = (const float*)d_in[0];
  const float* Wq_w = (const float*)d_in[1];
  const float* Wq_b = (const float*)d_in[2];
  const float* Wk_w = (const float*)d_in[3];
  const float* Wk_b = (const float*)d_in[4];
  const float* Wv_w = (const float*)d_in[5];
  const float* Wv_b = (const float*)d_in[6];
  const float* Wo_w = (const float*)d_in[7];
  const float* Wo_b = (const float*)d_in[8];
  float* out = (float*)d_out;                       // [Mm*Cc] + [Bb*Hh*11]
  float* attn_last = out + (size_t)Mm * Cc;

  // workspace carve (bytes)
  char* ws = (char*)d_ws;
  unsigned short* qb   = (unsigned short*)(ws);                       // Mm*Cc bf16   = 16 MB
  unsigned short* Wqkv = (unsigned short*)(ws + 16777216);            // 3072*1024    = 6 MB
  unsigned short* Wo16 = (unsigned short*)(ws + 16777216 + 6291456);  // 1024*1024    = 2 MB
  float*          bqkv = (float*)(ws + 25165824);                     // 3072 f32
  unsigned short* QKV  = (unsigned short*)(ws + 25182208);            // Mm*3072      = 48 MB
  unsigned short* AO   = (unsigned short*)(ws + 75513856);            // Mm*Cc        = 16 MB

  // 1) converts
  {
    int n4 = (Mm * Cc) / 4;
    f2bf_kernel<<<2048, 256, 0, stream>>>((const float4*)q, (us4*)qb, n4);
    int w4 = (Cc * Cc) / 4;
    f2bf_kernel<<<1024, 256, 0, stream>>>((const float4*)Wq_w, (us4*)(Wqkv), w4);
    f2bf_kernel<<<1024, 256, 0, stream>>>((const float4*)Wk_w, (us4*)(Wqkv + Cc * Cc), w4);
    f2bf_kernel<<<1024, 256, 0, stream>>>((const float4*)Wv_w, (us4*)(Wqkv + 2 * Cc * Cc), w4);
    f2bf_kernel<<<1024, 256, 0, stream>>>((const float4*)Wo_w, (us4*)Wo16, w4);
    hipMemcpyAsync(bqkv,          Wq_b, Cc * sizeof(float), hipMemcpyDeviceToDevice, stream);
    hipMemcpyAsync(bqkv + Cc,     Wk_b, Cc * sizeof(float), hipMemcpyDeviceToDevice, stream);
    hipMemcpyAsync(bqkv + 2 * Cc, Wv_b, Cc * sizeof(float), hipMemcpyDeviceToDevice, stream);
  }

  // 2) fused QKV projection: [8192,1024] x [3072,1024]^T -> bf16 [8192,3072]
  {
    dim3 grid(3072 / 128, Mm / 128);
    gemm_bt<true><<<grid, 256, 0, stream>>>(qb, Wqkv, bqkv, (void*)QKV, Mm, 3072, Cc);
  }

  // 3) windowed attention -> bf16 [8192,1024] + attn_last tail of d_out
  {
    dim3 grid(Bb * Hh * (Nn / TN));
    attn_kernel<<<grid, 128, 0, stream>>>(QKV, AO, attn_last);
  }

  // 4) output projection: [8192,1024] x [1024,1024]^T -> fp32 d_out
  {
    dim3 grid(Cc / 128, Mm / 128);
    gemm_bt<false><<<grid, 256, 0, stream>>>(AO, Wo16, Wo_b, (void*)out, Mm, Cc, Cc);
  }
}